// Round 2
// baseline (2961.679 us; speedup 1.0000x reference)
//
#include <hip/hip_runtime.h>
#include <hip/hip_fp16.h>

// Unidir_LSTM: h_t = sig(o)*tanh(sig(i)*tanh(g)); f-gate dead (cell carry always 0).
// R1 post-mortem: cooperative launch suspected to fail silently (out was all-zero).
// R2: plain launch, 256 blocks (16 rows x 32 cols), 39KB LDS, __fp16 vectors,
//     release/acquire agent-scope flags. Forward-only dataflow, all blocks resident.

typedef __fp16 f16x8 __attribute__((ext_vector_type(8)));
typedef __fp16 f16x4 __attribute__((ext_vector_type(4)));
typedef float  f32x4 __attribute__((ext_vector_type(4)));

#define MFMA16(a, b, c) __builtin_amdgcn_mfma_f32_16x16x32_f16(a, b, c, 0, 0, 0)

__device__ __forceinline__ void gload_lds16(const void* g, void* l) {
  // async global->LDS, 16B/lane; LDS dest = wave-uniform base + lane*16
  __builtin_amdgcn_global_load_lds(
      (const __attribute__((address_space(1))) unsigned int*)g,
      (__attribute__((address_space(3))) unsigned int*)l, 16, 0, 0);
}

__device__ __forceinline__ float sigmoid_f(float x) {
  return 1.f / (1.f + __expf(-x));
}
__device__ __forceinline__ float tanh_f(float x) {
  x = fminf(fmaxf(x, -15.f), 15.f);
  float e = __expf(2.f * x);
  return (e - 1.f) / (e + 1.f);
}

static constexpr int SS = 256, NG = 3072;  // NG = 3H (gates i,g,o; f is dead)

// ---------------- prep: pack W_ih/W_hh rows {i,g,o} to fp16, bias3 = b_ih+b_hh ----
__global__ void prep_kernel(const float* __restrict__ W_ih, const float* __restrict__ W_hh,
                            const float* __restrict__ b_ih, const float* __restrict__ b_hh,
                            __fp16* __restrict__ Wi3, __fp16* __restrict__ Wh3,
                            float* __restrict__ bias3) {
  int j3 = blockIdx.x;                 // 0..3071 packed row
  int g = j3 >> 10, j = j3 & 1023;
  int orig = (g == 0 ? 0 : (g == 1 ? 2048 : 3072)) + j;  // i,g,o rows of 4H
  int tid = threadIdx.x;
  {
    float4 v = *(const float4*)(W_hh + (size_t)orig * 1024 + tid * 4);
    f16x4 o = {(__fp16)v.x, (__fp16)v.y, (__fp16)v.z, (__fp16)v.w};
    *(f16x4*)(Wh3 + (size_t)j3 * 1024 + tid * 4) = o;
  }
  if (tid < 128) {
    float4 v = *(const float4*)(W_ih + (size_t)orig * 512 + tid * 4);
    f16x4 o = {(__fp16)v.x, (__fp16)v.y, (__fp16)v.z, (__fp16)v.w};
    *(f16x4*)(Wi3 + (size_t)j3 * 512 + tid * 4) = o;
  }
  if (tid == 0) bias3[j3] = b_ih[orig] + b_hh[orig];
}

// ---------------- gather: X[t*128+b][e] = fp16(embed[tok[b][t]][e]) ----------------
__global__ void gather_kernel(const int* __restrict__ tok, const float* __restrict__ emb,
                              __fp16* __restrict__ X) {
  int m = blockIdx.x;                  // 0..32767 = t*128 + b
  int t = m >> 7, b = m & 127;
  int tk = tok[b * SS + t];            // inputs is [B][S]
  int e0 = threadIdx.x * 8;
  const float* src = emb + (size_t)tk * 512 + e0;
  float4 v0 = *(const float4*)src;
  float4 v1 = *(const float4*)(src + 4);
  f16x8 o;
  o[0] = (__fp16)v0.x; o[1] = (__fp16)v0.y; o[2] = (__fp16)v0.z; o[3] = (__fp16)v0.w;
  o[4] = (__fp16)v1.x; o[5] = (__fp16)v1.y; o[6] = (__fp16)v1.z; o[7] = (__fp16)v1.w;
  *(f16x8*)(X + (size_t)m * 512 + e0) = o;
}

// ---------------- Xp GEMM: Xp[m][n] = sum_k X[m][k]*Wi3[n][k] + bias3[n] ----------
// 128x128 tile, BK=32, 4 waves 64x64 each, m97-style global_load_lds staging.
__global__ __launch_bounds__(256) void xp_gemm(const __fp16* __restrict__ X,
                                               const __fp16* __restrict__ Wi3,
                                               const float* __restrict__ bias3,
                                               __fp16* __restrict__ Xp) {
  __shared__ __align__(16) __fp16 As[128 * 32];
  __shared__ __align__(16) __fp16 Bs[128 * 32];
  int bid = blockIdx.x;
  int bm = bid / 24, bn = bid % 24;
  int m0 = bm * 128, n0 = bn * 128;
  int tid = threadIdx.x, wid = tid >> 6, lane = tid & 63;
  int wm = wid & 1, wn = wid >> 1;
  int l15 = lane & 15, quad = lane >> 4;
  int lr = lane >> 2, lc = lane & 3;   // staging: 16 rows x 4 segs per wave-call
  f32x4 acc[4][4];
#pragma unroll
  for (int mt = 0; mt < 4; ++mt)
#pragma unroll
    for (int nt = 0; nt < 4; ++nt) {
      f32x4 z = {0.f, 0.f, 0.f, 0.f};
      acc[mt][nt] = z;
    }

  for (int k0 = 0; k0 < 512; k0 += 32) {
    __syncthreads();
#pragma unroll
    for (int c = 0; c < 2; ++c) {
      int row = wid * 32 + c * 16;
      gload_lds16(X   + (size_t)(m0 + row + lr) * 512 + k0 + lc * 8, (void*)(As + row * 32));
      gload_lds16(Wi3 + (size_t)(n0 + row + lr) * 512 + k0 + lc * 8, (void*)(Bs + row * 32));
    }
    __syncthreads();
    f16x8 af[4], bfr[4];
#pragma unroll
    for (int mt = 0; mt < 4; ++mt)
      af[mt] = *(const f16x8*)(As + (wm * 64 + mt * 16 + l15) * 32 + quad * 8);
#pragma unroll
    for (int nt = 0; nt < 4; ++nt)
      bfr[nt] = *(const f16x8*)(Bs + (wn * 64 + nt * 16 + l15) * 32 + quad * 8);
#pragma unroll
    for (int mt = 0; mt < 4; ++mt)
#pragma unroll
      for (int nt = 0; nt < 4; ++nt)
        acc[mt][nt] = MFMA16(af[mt], bfr[nt], acc[mt][nt]);
  }
#pragma unroll
  for (int nt = 0; nt < 4; ++nt) {
    int col = n0 + wn * 64 + nt * 16 + l15;
    float bv = bias3[col];
#pragma unroll
    for (int mt = 0; mt < 4; ++mt) {
#pragma unroll
      for (int r = 0; r < 4; ++r) {
        int row = m0 + wm * 64 + mt * 16 + quad * 4 + r;  // C/D: col=lane&15, row=quad*4+reg
        Xp[(size_t)row * NG + col] = (__fp16)(acc[mt][nt][r] + bv);
      }
    }
  }
}

// ---------------- recurrence: persistent, W_hh register-resident, flag dataflow ----
// 256 blocks = (bg 0..7: 16 batch rows) x (n 0..31: 32 h-cols). Plain launch:
// 39KB LDS + <=512 VGPR/wave @ 4 waves/block => >=2 blocks/CU fit => all 256
// resident => forward-only dataflow can't deadlock.
// 4 waves = (ch 0..1: 16-col half) x (kh 0..1: 512-K half). Per wave: B-frags for
// 3 gates x 16 k-steps = 192 VGPRs, loaded once, reused all 256 steps.
__global__ __launch_bounds__(256, 1) void recur_kernel(const __fp16* __restrict__ Wh3,
                                                       const __fp16* __restrict__ Xp,
                                                       __fp16* __restrict__ hbuf,
                                                       int* __restrict__ flags,
                                                       float* __restrict__ out) {
  int bid = blockIdx.x;
  int bg = bid >> 5, n = bid & 31;
  int b0 = bg * 16, j0 = n * 32;
  int tid = threadIdx.x, wid = tid >> 6, lane = tid & 63;
  int ch = wid & 1, kh = wid >> 1;
  int l15 = lane & 15, quad = lane >> 4;
  const int mycol = j0 + ch * 16 + l15;

  __shared__ __align__(16) unsigned char Asub[16 * 2064];  // 16 h-rows, 2048B + 16B pad
  __shared__ float gbuf[2][3][16][16];                     // K-half partial exchange

  // persistent W fragments: wf[g][kk] = Wh3 row (g*1024+mycol), k = kh*512+kk*32+quad*8
  f16x8 wf[3][16];
#pragma unroll
  for (int g = 0; g < 3; ++g) {
    const __fp16* wr = Wh3 + (size_t)(g * 1024 + mycol) * 1024 + kh * 512 + quad * 8;
#pragma unroll
    for (int kk = 0; kk < 16; ++kk) wf[g][kk] = *(const f16x8*)(wr + kk * 32);
  }

  for (int t = 0; t < SS; ++t) {
    // (a) preload Xp (+bias folded in) into kh0 accumulators — no h dependency,
    //     overlaps the flag spin below
    f32x4 acc[3];
#pragma unroll
    for (int g = 0; g < 3; ++g) {
      f32x4 z = {0.f, 0.f, 0.f, 0.f};
      acc[g] = z;
    }
    if (kh == 0) {
#pragma unroll
      for (int g = 0; g < 3; ++g)
#pragma unroll
        for (int r = 0; r < 4; ++r)
          acc[g][r] = (float)Xp[(size_t)(t * 128 + b0 + quad * 4 + r) * NG + g * 1024 + mycol];
    }
    // (b) wait for the 32 producers of our batch group (lane <-> producer col-group)
    if (t > 0 && wid == 0) {
      const int fidx = (bg * 32 + (lane & 31)) * 16;
      for (;;) {
        int v = __hip_atomic_load(flags + fidx, __ATOMIC_ACQUIRE, __HIP_MEMORY_SCOPE_AGENT);
        if (__ballot(v < t) == 0ull) break;
        __builtin_amdgcn_s_sleep(2);
      }
    }
    __syncthreads();
    // (c) stage h_t[b0..b0+15][0..1023] fp16 -> LDS: 32 chunks of 1KB, 8 per wave
    {
      const __fp16* hsrc = hbuf + (size_t)t * 131072 + (size_t)b0 * 1024;
#pragma unroll
      for (int i = 0; i < 8; ++i) {
        int c = wid * 8 + i;
        int row = c >> 1, half = c & 1;
        gload_lds16(hsrc + row * 1024 + half * 512 + lane * 8,
                    (void*)(Asub + row * 2064 + half * 1024));
      }
    }
    __syncthreads();
    // (d) MFMA: A from LDS, B from persistent registers; 3 interleaved gate chains
    {
      const unsigned char* abase = Asub + l15 * 2064 + (kh * 512 + quad * 8) * 2;
#pragma unroll
      for (int kk = 0; kk < 16; ++kk) {
        f16x8 af = *(const f16x8*)(abase + kk * 64);
        acc[0] = MFMA16(af, wf[0][kk], acc[0]);
        acc[1] = MFMA16(af, wf[1][kk], acc[1]);
        acc[2] = MFMA16(af, wf[2][kk], acc[2]);
      }
    }
    // (e) K-half reduction via LDS, activation epilogue on kh1 waves
    if (kh == 0) {
#pragma unroll
      for (int g = 0; g < 3; ++g)
#pragma unroll
        for (int r = 0; r < 4; ++r) gbuf[ch][g][quad * 4 + r][l15] = acc[g][r];
    }
    __syncthreads();
    if (kh == 1) {
#pragma unroll
      for (int r = 0; r < 4; ++r) {
        float gi = acc[0][r] + gbuf[ch][0][quad * 4 + r][l15];
        float gg = acc[1][r] + gbuf[ch][1][quad * 4 + r][l15];
        float go = acc[2][r] + gbuf[ch][2][quad * 4 + r][l15];
        float ct = sigmoid_f(gi) * tanh_f(gg);
        float hN = sigmoid_f(go) * tanh_f(ct);
        int row = b0 + quad * 4 + r;
        if (t == SS - 1) out[(size_t)row * 1024 + mycol] = hN;
        else hbuf[(size_t)(t + 1) * 131072 + (size_t)row * 1024 + mycol] = (__fp16)hN;
      }
    }
    __syncthreads();  // barrier drains vmcnt: h stores in L2 before the release below
    if (t < SS - 1 && tid == 0) {
      // agent-scope release: writes back this XCD's L2 (covers all waves' h stores)
      __hip_atomic_store(flags + (bg * 32 + n) * 16, t + 1,
                         __ATOMIC_RELEASE, __HIP_MEMORY_SCOPE_AGENT);
    }
  }
}

extern "C" void kernel_launch(void* const* d_in, const int* in_sizes, int n_in,
                              void* d_out, int out_size, void* d_ws, size_t ws_size,
                              hipStream_t stream) {
  const int*   tok  = (const int*)d_in[0];
  const float* emb  = (const float*)d_in[1];
  const float* W_ih = (const float*)d_in[2];
  const float* W_hh = (const float*)d_in[3];
  const float* b_ih = (const float*)d_in[4];
  const float* b_hh = (const float*)d_in[5];
  float* out = (float*)d_out;
  char* ws = (char*)d_ws;

  // ws layout (bytes), total 311,455,744 (~297 MB)
  __fp16* X     = (__fp16*)(ws + 0);              // 33,554,432
  __fp16* Wi3   = (__fp16*)(ws + 33554432);       //  3,145,728
  __fp16* Wh3   = (__fp16*)(ws + 36700160);       //  6,291,456
  float*  bias3 = (float*) (ws + 42991616);       //     12,288
  int*    flags = (int*)   (ws + 43003904);       //     16,384 (256 flags, 64B apart)
  __fp16* hbuf  = (__fp16*)(ws + 43020288);       // 67,108,864 (256 step buffers)
  __fp16* Xp    = (__fp16*)(ws + 110129152);      // 201,326,592

  hipMemsetAsync(flags, 0, 16384, stream);
  hipMemsetAsync(hbuf, 0, 131072 * 2, stream);    // h_0 = 0

  prep_kernel<<<3072, 256, 0, stream>>>(W_ih, W_hh, b_ih, b_hh, Wi3, Wh3, bias3);
  gather_kernel<<<32768, 64, 0, stream>>>(tok, emb, X);
  xp_gemm<<<6144, 256, 0, stream>>>(X, Wi3, bias3, Xp);
  recur_kernel<<<256, 256, 0, stream>>>(Wh3, Xp, hbuf, flags, out);
}

// Round 4
// 2759.623 us; speedup vs baseline: 1.0732x; 1.0732x over previous
//
#include <hip/hip_runtime.h>
#include <hip/hip_fp16.h>

// Unidir_LSTM: h_t = sig(o)*tanh(sig(i)*tanh(g)); f-gate dead (cell carry always 0).
// R2: correct, 2735us recur — latency-bound handoff (MfmaUtil 3%). Acquire-per-poll
//     emitted buffer_inv per iteration (L2 thrash), and batch groups spanned XCDs.
// R3: relaxed spin + single acquire fence; XCD-local batch groups (bg = bid & 7,
//     round-robin block->XCD mapping) so h exchange stays in one XCD's L2.
// R4: fix compile — fence spelling is __builtin_amdgcn_fence(order, "agent").

typedef __fp16 f16x8 __attribute__((ext_vector_type(8)));
typedef __fp16 f16x4 __attribute__((ext_vector_type(4)));
typedef float  f32x4 __attribute__((ext_vector_type(4)));

#define MFMA16(a, b, c) __builtin_amdgcn_mfma_f32_16x16x32_f16(a, b, c, 0, 0, 0)

__device__ __forceinline__ void gload_lds16(const void* g, void* l) {
  // async global->LDS, 16B/lane; LDS dest = wave-uniform base + lane*16
  __builtin_amdgcn_global_load_lds(
      (const __attribute__((address_space(1))) unsigned int*)g,
      (__attribute__((address_space(3))) unsigned int*)l, 16, 0, 0);
}

__device__ __forceinline__ float sigmoid_f(float x) {
  return 1.f / (1.f + __expf(-x));
}
__device__ __forceinline__ float tanh_f(float x) {
  x = fminf(fmaxf(x, -15.f), 15.f);
  float e = __expf(2.f * x);
  return (e - 1.f) / (e + 1.f);
}

static constexpr int SS = 256, NG = 3072;  // NG = 3H (gates i,g,o; f is dead)

// ---------------- prep: pack W_ih/W_hh rows {i,g,o} to fp16, bias3 = b_ih+b_hh ----
__global__ void prep_kernel(const float* __restrict__ W_ih, const float* __restrict__ W_hh,
                            const float* __restrict__ b_ih, const float* __restrict__ b_hh,
                            __fp16* __restrict__ Wi3, __fp16* __restrict__ Wh3,
                            float* __restrict__ bias3) {
  int j3 = blockIdx.x;                 // 0..3071 packed row
  int g = j3 >> 10, j = j3 & 1023;
  int orig = (g == 0 ? 0 : (g == 1 ? 2048 : 3072)) + j;  // i,g,o rows of 4H
  int tid = threadIdx.x;
  {
    float4 v = *(const float4*)(W_hh + (size_t)orig * 1024 + tid * 4);
    f16x4 o = {(__fp16)v.x, (__fp16)v.y, (__fp16)v.z, (__fp16)v.w};
    *(f16x4*)(Wh3 + (size_t)j3 * 1024 + tid * 4) = o;
  }
  if (tid < 128) {
    float4 v = *(const float4*)(W_ih + (size_t)orig * 512 + tid * 4);
    f16x4 o = {(__fp16)v.x, (__fp16)v.y, (__fp16)v.z, (__fp16)v.w};
    *(f16x4*)(Wi3 + (size_t)j3 * 512 + tid * 4) = o;
  }
  if (tid == 0) bias3[j3] = b_ih[orig] + b_hh[orig];
}

// ---------------- gather: X[t*128+b][e] = fp16(embed[tok[b][t]][e]) ----------------
__global__ void gather_kernel(const int* __restrict__ tok, const float* __restrict__ emb,
                              __fp16* __restrict__ X) {
  int m = blockIdx.x;                  // 0..32767 = t*128 + b
  int t = m >> 7, b = m & 127;
  int tk = tok[b * SS + t];            // inputs is [B][S]
  int e0 = threadIdx.x * 8;
  const float* src = emb + (size_t)tk * 512 + e0;
  float4 v0 = *(const float4*)src;
  float4 v1 = *(const float4*)(src + 4);
  f16x8 o;
  o[0] = (__fp16)v0.x; o[1] = (__fp16)v0.y; o[2] = (__fp16)v0.z; o[3] = (__fp16)v0.w;
  o[4] = (__fp16)v1.x; o[5] = (__fp16)v1.y; o[6] = (__fp16)v1.z; o[7] = (__fp16)v1.w;
  *(f16x8*)(X + (size_t)m * 512 + e0) = o;
}

// ---------------- Xp GEMM: Xp[m][n] = sum_k X[m][k]*Wi3[n][k] + bias3[n] ----------
// 128x128 tile, BK=32, 4 waves 64x64 each, m97-style global_load_lds staging.
__global__ __launch_bounds__(256) void xp_gemm(const __fp16* __restrict__ X,
                                               const __fp16* __restrict__ Wi3,
                                               const float* __restrict__ bias3,
                                               __fp16* __restrict__ Xp) {
  __shared__ __align__(16) __fp16 As[128 * 32];
  __shared__ __align__(16) __fp16 Bs[128 * 32];
  int bid = blockIdx.x;
  int bm = bid / 24, bn = bid % 24;
  int m0 = bm * 128, n0 = bn * 128;
  int tid = threadIdx.x, wid = tid >> 6, lane = tid & 63;
  int wm = wid & 1, wn = wid >> 1;
  int l15 = lane & 15, quad = lane >> 4;
  int lr = lane >> 2, lc = lane & 3;   // staging: 16 rows x 4 segs per wave-call
  f32x4 acc[4][4];
#pragma unroll
  for (int mt = 0; mt < 4; ++mt)
#pragma unroll
    for (int nt = 0; nt < 4; ++nt) {
      f32x4 z = {0.f, 0.f, 0.f, 0.f};
      acc[mt][nt] = z;
    }

  for (int k0 = 0; k0 < 512; k0 += 32) {
    __syncthreads();
#pragma unroll
    for (int c = 0; c < 2; ++c) {
      int row = wid * 32 + c * 16;
      gload_lds16(X   + (size_t)(m0 + row + lr) * 512 + k0 + lc * 8, (void*)(As + row * 32));
      gload_lds16(Wi3 + (size_t)(n0 + row + lr) * 512 + k0 + lc * 8, (void*)(Bs + row * 32));
    }
    __syncthreads();
    f16x8 af[4], bfr[4];
#pragma unroll
    for (int mt = 0; mt < 4; ++mt)
      af[mt] = *(const f16x8*)(As + (wm * 64 + mt * 16 + l15) * 32 + quad * 8);
#pragma unroll
    for (int nt = 0; nt < 4; ++nt)
      bfr[nt] = *(const f16x8*)(Bs + (wn * 64 + nt * 16 + l15) * 32 + quad * 8);
#pragma unroll
    for (int mt = 0; mt < 4; ++mt)
#pragma unroll
      for (int nt = 0; nt < 4; ++nt)
        acc[mt][nt] = MFMA16(af[mt], bfr[nt], acc[mt][nt]);
  }
#pragma unroll
  for (int nt = 0; nt < 4; ++nt) {
    int col = n0 + wn * 64 + nt * 16 + l15;
    float bv = bias3[col];
#pragma unroll
    for (int mt = 0; mt < 4; ++mt) {
#pragma unroll
      for (int r = 0; r < 4; ++r) {
        int row = m0 + wm * 64 + mt * 16 + quad * 4 + r;  // C/D: col=lane&15, row=quad*4+reg
        Xp[(size_t)row * NG + col] = (__fp16)(acc[mt][nt][r] + bv);
      }
    }
  }
}

// ---------------- recurrence: persistent, W_hh register-resident, flag dataflow ----
// 256 blocks = (bg 0..7: 16 batch rows) x (n 0..31: 32 h-cols). bg = bid & 7 so all
// 32 blocks of a batch group land on one XCD (round-robin dispatch heuristic) — the
// h exchange then stays in that XCD's L2. Agent-scope atomics keep it correct even
// if the mapping differs. Plain launch: 39KB LDS, 4 waves => all 256 resident.
// 4 waves = (ch 0..1: 16-col half) x (kh 0..1: 512-K half). Per wave: B-frags for
// 3 gates x 16 k-steps = 192 VGPRs, loaded once, reused all 256 steps.
__global__ __launch_bounds__(256, 1) void recur_kernel(const __fp16* __restrict__ Wh3,
                                                       const __fp16* __restrict__ Xp,
                                                       __fp16* __restrict__ hbuf,
                                                       int* __restrict__ flags,
                                                       float* __restrict__ out) {
  int bid = blockIdx.x;
  int bg = bid & 7, n = bid >> 3;      // XCD-local batch groups
  int b0 = bg * 16, j0 = n * 32;
  int tid = threadIdx.x, wid = tid >> 6, lane = tid & 63;
  int ch = wid & 1, kh = wid >> 1;
  int l15 = lane & 15, quad = lane >> 4;
  const int mycol = j0 + ch * 16 + l15;

  __shared__ __align__(16) unsigned char Asub[16 * 2064];  // 16 h-rows, 2048B + 16B pad
  __shared__ float gbuf[2][3][16][16];                     // K-half partial exchange

  // persistent W fragments: wf[g][kk] = Wh3 row (g*1024+mycol), k = kh*512+kk*32+quad*8
  f16x8 wf[3][16];
#pragma unroll
  for (int g = 0; g < 3; ++g) {
    const __fp16* wr = Wh3 + (size_t)(g * 1024 + mycol) * 1024 + kh * 512 + quad * 8;
#pragma unroll
    for (int kk = 0; kk < 16; ++kk) wf[g][kk] = *(const f16x8*)(wr + kk * 32);
  }

  for (int t = 0; t < SS; ++t) {
    // (a) preload Xp (+bias folded in) into kh0 accumulators — no h dependency,
    //     issues before the spin so it overlaps the wait
    f32x4 acc[3];
#pragma unroll
    for (int g = 0; g < 3; ++g) {
      f32x4 z = {0.f, 0.f, 0.f, 0.f};
      acc[g] = z;
    }
    if (kh == 0) {
#pragma unroll
      for (int g = 0; g < 3; ++g)
#pragma unroll
        for (int r = 0; r < 4; ++r)
          acc[g][r] = (float)Xp[(size_t)(t * 128 + b0 + quad * 4 + r) * NG + g * 1024 + mycol];
    }
    // (b) wait for the 32 producers of our batch group: RELAXED polls (no buffer_inv
    //     per iteration), one ACQUIRE fence once satisfied
    if (t > 0 && wid == 0) {
      const int fidx = (bg * 32 + (lane & 31)) * 16;
      for (;;) {
        int v = __hip_atomic_load(flags + fidx, __ATOMIC_RELAXED, __HIP_MEMORY_SCOPE_AGENT);
        if (__ballot(v < t) == 0ull) break;
        __builtin_amdgcn_s_sleep(1);
      }
      __builtin_amdgcn_fence(__ATOMIC_ACQUIRE, "agent");
    }
    __syncthreads();
    // (c) stage h_t[b0..b0+15][0..1023] fp16 -> LDS: 32 chunks of 1KB, 8 per wave
    {
      const __fp16* hsrc = hbuf + (size_t)t * 131072 + (size_t)b0 * 1024;
#pragma unroll
      for (int i = 0; i < 8; ++i) {
        int c = wid * 8 + i;
        int row = c >> 1, half = c & 1;
        gload_lds16(hsrc + row * 1024 + half * 512 + lane * 8,
                    (void*)(Asub + row * 2064 + half * 1024));
      }
    }
    __syncthreads();
    // (d) MFMA: A from LDS, B from persistent registers; 3 interleaved gate chains
    {
      const unsigned char* abase = Asub + l15 * 2064 + (kh * 512 + quad * 8) * 2;
#pragma unroll
      for (int kk = 0; kk < 16; ++kk) {
        f16x8 af = *(const f16x8*)(abase + kk * 64);
        acc[0] = MFMA16(af, wf[0][kk], acc[0]);
        acc[1] = MFMA16(af, wf[1][kk], acc[1]);
        acc[2] = MFMA16(af, wf[2][kk], acc[2]);
      }
    }
    // (e) K-half reduction via LDS, activation epilogue on kh1 waves
    if (kh == 0) {
#pragma unroll
      for (int g = 0; g < 3; ++g)
#pragma unroll
        for (int r = 0; r < 4; ++r) gbuf[ch][g][quad * 4 + r][l15] = acc[g][r];
    }
    __syncthreads();
    if (kh == 1) {
#pragma unroll
      for (int r = 0; r < 4; ++r) {
        float gi = acc[0][r] + gbuf[ch][0][quad * 4 + r][l15];
        float gg = acc[1][r] + gbuf[ch][1][quad * 4 + r][l15];
        float go = acc[2][r] + gbuf[ch][2][quad * 4 + r][l15];
        float ct = sigmoid_f(gi) * tanh_f(gg);
        float hN = sigmoid_f(go) * tanh_f(ct);
        int row = b0 + quad * 4 + r;
        if (t == SS - 1) out[(size_t)row * 1024 + mycol] = hN;
        else hbuf[(size_t)(t + 1) * 131072 + (size_t)row * 1024 + mycol] = (__fp16)hN;
      }
    }
    __syncthreads();  // all waves' h stores done (each waited own vmcnt) before release
    if (t < SS - 1 && tid == 0) {
      // agent-scope release: wbL2 covers the whole block's h stores, then flag store
      __hip_atomic_store(flags + (bg * 32 + n) * 16, t + 1,
                         __ATOMIC_RELEASE, __HIP_MEMORY_SCOPE_AGENT);
    }
  }
}

extern "C" void kernel_launch(void* const* d_in, const int* in_sizes, int n_in,
                              void* d_out, int out_size, void* d_ws, size_t ws_size,
                              hipStream_t stream) {
  const int*   tok  = (const int*)d_in[0];
  const float* emb  = (const float*)d_in[1];
  const float* W_ih = (const float*)d_in[2];
  const float* W_hh = (const float*)d_in[3];
  const float* b_ih = (const float*)d_in[4];
  const float* b_hh = (const float*)d_in[5];
  float* out = (float*)d_out;
  char* ws = (char*)d_ws;

  // ws layout (bytes), total 311,455,744 (~297 MB)
  __fp16* X     = (__fp16*)(ws + 0);              // 33,554,432
  __fp16* Wi3   = (__fp16*)(ws + 33554432);       //  3,145,728
  __fp16* Wh3   = (__fp16*)(ws + 36700160);       //  6,291,456
  float*  bias3 = (float*) (ws + 42991616);       //     12,288
  int*    flags = (int*)   (ws + 43003904);       //     16,384 (256 flags, 64B apart)
  __fp16* hbuf  = (__fp16*)(ws + 43020288);       // 67,108,864 (256 step buffers)
  __fp16* Xp    = (__fp16*)(ws + 110129152);      // 201,326,592

  (void)hipMemsetAsync(flags, 0, 16384, stream);
  (void)hipMemsetAsync(hbuf, 0, 131072 * 2, stream);  // h_0 = 0

  prep_kernel<<<3072, 256, 0, stream>>>(W_ih, W_hh, b_ih, b_hh, Wi3, Wh3, bias3);
  gather_kernel<<<32768, 64, 0, stream>>>(tok, emb, X);
  xp_gemm<<<6144, 256, 0, stream>>>(X, Wi3, bias3, Xp);
  recur_kernel<<<256, 256, 0, stream>>>(Wh3, Xp, hbuf, flags, out);
}

// Round 5
// 1621.315 us; speedup vs baseline: 1.8267x; 1.7021x over previous
//
#include <hip/hip_runtime.h>
#include <hip/hip_fp16.h>

// Unidir_LSTM: h_t = sig(o)*tanh(sig(i)*tanh(g)); f-gate dead (cell carry always 0).
// R2: correct, 2735us recur — latency-bound handoff (MfmaUtil 3%).
// R4: relaxed polls + single acquire fence: FETCH 481->158MB but time ~same =>
//     poll-side invalidates were off the critical path. WRITE=67.8MB == full h
//     history to HBM => producer's agent-RELEASE (s_waitcnt + buffer_wbl2 per block
//     per step, 32 serializing per XCD L2) is the ~10us/step.
// R5: demote release to RELAXED agent flag store (no wbl2). h handoff stays in the
//     shared XCD L2 (bg = bid & 7 keeps each batch group on one XCD; flags go via IF
//     in both directions). Consumer keeps once-per-step acquire fence (L1 safety).
//     Signature if theory right: WRITE_SIZE collapses to ~2MB and step time ~3x down.

typedef __fp16 f16x8 __attribute__((ext_vector_type(8)));
typedef __fp16 f16x4 __attribute__((ext_vector_type(4)));
typedef float  f32x4 __attribute__((ext_vector_type(4)));

#define MFMA16(a, b, c) __builtin_amdgcn_mfma_f32_16x16x32_f16(a, b, c, 0, 0, 0)

__device__ __forceinline__ void gload_lds16(const void* g, void* l) {
  // async global->LDS, 16B/lane; LDS dest = wave-uniform base + lane*16
  __builtin_amdgcn_global_load_lds(
      (const __attribute__((address_space(1))) unsigned int*)g,
      (__attribute__((address_space(3))) unsigned int*)l, 16, 0, 0);
}

__device__ __forceinline__ float sigmoid_f(float x) {
  return 1.f / (1.f + __expf(-x));
}
__device__ __forceinline__ float tanh_f(float x) {
  x = fminf(fmaxf(x, -15.f), 15.f);
  float e = __expf(2.f * x);
  return (e - 1.f) / (e + 1.f);
}

static constexpr int SS = 256, NG = 3072;  // NG = 3H (gates i,g,o; f is dead)

// ---------------- prep: pack W_ih/W_hh rows {i,g,o} to fp16, bias3 = b_ih+b_hh ----
__global__ void prep_kernel(const float* __restrict__ W_ih, const float* __restrict__ W_hh,
                            const float* __restrict__ b_ih, const float* __restrict__ b_hh,
                            __fp16* __restrict__ Wi3, __fp16* __restrict__ Wh3,
                            float* __restrict__ bias3) {
  int j3 = blockIdx.x;                 // 0..3071 packed row
  int g = j3 >> 10, j = j3 & 1023;
  int orig = (g == 0 ? 0 : (g == 1 ? 2048 : 3072)) + j;  // i,g,o rows of 4H
  int tid = threadIdx.x;
  {
    float4 v = *(const float4*)(W_hh + (size_t)orig * 1024 + tid * 4);
    f16x4 o = {(__fp16)v.x, (__fp16)v.y, (__fp16)v.z, (__fp16)v.w};
    *(f16x4*)(Wh3 + (size_t)j3 * 1024 + tid * 4) = o;
  }
  if (tid < 128) {
    float4 v = *(const float4*)(W_ih + (size_t)orig * 512 + tid * 4);
    f16x4 o = {(__fp16)v.x, (__fp16)v.y, (__fp16)v.z, (__fp16)v.w};
    *(f16x4*)(Wi3 + (size_t)j3 * 512 + tid * 4) = o;
  }
  if (tid == 0) bias3[j3] = b_ih[orig] + b_hh[orig];
}

// ---------------- gather: X[t*128+b][e] = fp16(embed[tok[b][t]][e]) ----------------
__global__ void gather_kernel(const int* __restrict__ tok, const float* __restrict__ emb,
                              __fp16* __restrict__ X) {
  int m = blockIdx.x;                  // 0..32767 = t*128 + b
  int t = m >> 7, b = m & 127;
  int tk = tok[b * SS + t];            // inputs is [B][S]
  int e0 = threadIdx.x * 8;
  const float* src = emb + (size_t)tk * 512 + e0;
  float4 v0 = *(const float4*)src;
  float4 v1 = *(const float4*)(src + 4);
  f16x8 o;
  o[0] = (__fp16)v0.x; o[1] = (__fp16)v0.y; o[2] = (__fp16)v0.z; o[3] = (__fp16)v0.w;
  o[4] = (__fp16)v1.x; o[5] = (__fp16)v1.y; o[6] = (__fp16)v1.z; o[7] = (__fp16)v1.w;
  *(f16x8*)(X + (size_t)m * 512 + e0) = o;
}

// ---------------- Xp GEMM: Xp[m][n] = sum_k X[m][k]*Wi3[n][k] + bias3[n] ----------
// 128x128 tile, BK=32, 4 waves 64x64 each, m97-style global_load_lds staging.
__global__ __launch_bounds__(256) void xp_gemm(const __fp16* __restrict__ X,
                                               const __fp16* __restrict__ Wi3,
                                               const float* __restrict__ bias3,
                                               __fp16* __restrict__ Xp) {
  __shared__ __align__(16) __fp16 As[128 * 32];
  __shared__ __align__(16) __fp16 Bs[128 * 32];
  int bid = blockIdx.x;
  int bm = bid / 24, bn = bid % 24;
  int m0 = bm * 128, n0 = bn * 128;
  int tid = threadIdx.x, wid = tid >> 6, lane = tid & 63;
  int wm = wid & 1, wn = wid >> 1;
  int l15 = lane & 15, quad = lane >> 4;
  int lr = lane >> 2, lc = lane & 3;   // staging: 16 rows x 4 segs per wave-call
  f32x4 acc[4][4];
#pragma unroll
  for (int mt = 0; mt < 4; ++mt)
#pragma unroll
    for (int nt = 0; nt < 4; ++nt) {
      f32x4 z = {0.f, 0.f, 0.f, 0.f};
      acc[mt][nt] = z;
    }

  for (int k0 = 0; k0 < 512; k0 += 32) {
    __syncthreads();
#pragma unroll
    for (int c = 0; c < 2; ++c) {
      int row = wid * 32 + c * 16;
      gload_lds16(X   + (size_t)(m0 + row + lr) * 512 + k0 + lc * 8, (void*)(As + row * 32));
      gload_lds16(Wi3 + (size_t)(n0 + row + lr) * 512 + k0 + lc * 8, (void*)(Bs + row * 32));
    }
    __syncthreads();
    f16x8 af[4], bfr[4];
#pragma unroll
    for (int mt = 0; mt < 4; ++mt)
      af[mt] = *(const f16x8*)(As + (wm * 64 + mt * 16 + l15) * 32 + quad * 8);
#pragma unroll
    for (int nt = 0; nt < 4; ++nt)
      bfr[nt] = *(const f16x8*)(Bs + (wn * 64 + nt * 16 + l15) * 32 + quad * 8);
#pragma unroll
    for (int mt = 0; mt < 4; ++mt)
#pragma unroll
      for (int nt = 0; nt < 4; ++nt)
        acc[mt][nt] = MFMA16(af[mt], bfr[nt], acc[mt][nt]);
  }
#pragma unroll
  for (int nt = 0; nt < 4; ++nt) {
    int col = n0 + wn * 64 + nt * 16 + l15;
    float bv = bias3[col];
#pragma unroll
    for (int mt = 0; mt < 4; ++mt) {
#pragma unroll
      for (int r = 0; r < 4; ++r) {
        int row = m0 + wm * 64 + mt * 16 + quad * 4 + r;  // C/D: col=lane&15, row=quad*4+reg
        Xp[(size_t)row * NG + col] = (__fp16)(acc[mt][nt][r] + bv);
      }
    }
  }
}

// ---------------- recurrence: persistent, W_hh register-resident, flag dataflow ----
// 256 blocks = (bg 0..7: 16 batch rows) x (n 0..31: 32 h-cols). bg = bid & 7 so all
// 32 blocks of a batch group land on one XCD (round-robin dispatch heuristic) — the
// h exchange stays in that XCD's L2 (plain stores drained by __syncthreads vmcnt).
// Flags are agent-scope atomics (execute at IF, both sides) — visibility safe.
// 4 waves = (ch 0..1: 16-col half) x (kh 0..1: 512-K half). Per wave: B-frags for
// 3 gates x 16 k-steps = 192 VGPRs, loaded once, reused all 256 steps.
__global__ __launch_bounds__(256, 1) void recur_kernel(const __fp16* __restrict__ Wh3,
                                                       const __fp16* __restrict__ Xp,
                                                       __fp16* __restrict__ hbuf,
                                                       int* __restrict__ flags,
                                                       float* __restrict__ out) {
  int bid = blockIdx.x;
  int bg = bid & 7, n = bid >> 3;      // XCD-local batch groups
  int b0 = bg * 16, j0 = n * 32;
  int tid = threadIdx.x, wid = tid >> 6, lane = tid & 63;
  int ch = wid & 1, kh = wid >> 1;
  int l15 = lane & 15, quad = lane >> 4;
  const int mycol = j0 + ch * 16 + l15;

  __shared__ __align__(16) unsigned char Asub[16 * 2064];  // 16 h-rows, 2048B + 16B pad
  __shared__ float gbuf[2][3][16][16];                     // K-half partial exchange

  // persistent W fragments: wf[g][kk] = Wh3 row (g*1024+mycol), k = kh*512+kk*32+quad*8
  f16x8 wf[3][16];
#pragma unroll
  for (int g = 0; g < 3; ++g) {
    const __fp16* wr = Wh3 + (size_t)(g * 1024 + mycol) * 1024 + kh * 512 + quad * 8;
#pragma unroll
    for (int kk = 0; kk < 16; ++kk) wf[g][kk] = *(const f16x8*)(wr + kk * 32);
  }

  for (int t = 0; t < SS; ++t) {
    // (a) preload Xp (+bias folded in) into kh0 accumulators — no h dependency,
    //     issues before the spin so it overlaps the wait
    f32x4 acc[3];
#pragma unroll
    for (int g = 0; g < 3; ++g) {
      f32x4 z = {0.f, 0.f, 0.f, 0.f};
      acc[g] = z;
    }
    if (kh == 0) {
#pragma unroll
      for (int g = 0; g < 3; ++g)
#pragma unroll
        for (int r = 0; r < 4; ++r)
          acc[g][r] = (float)Xp[(size_t)(t * 128 + b0 + quad * 4 + r) * NG + g * 1024 + mycol];
    }
    // (b) wait for the 32 producers of our batch group: RELAXED polls, one ACQUIRE
    //     fence once satisfied (L1 safety; h itself is fresh in the shared XCD L2)
    if (t > 0 && wid == 0) {
      const int fidx = (bg * 32 + (lane & 31)) * 16;
      for (;;) {
        int v = __hip_atomic_load(flags + fidx, __ATOMIC_RELAXED, __HIP_MEMORY_SCOPE_AGENT);
        if (__ballot(v < t) == 0ull) break;
        __builtin_amdgcn_s_sleep(1);
      }
      __builtin_amdgcn_fence(__ATOMIC_ACQUIRE, "agent");
    }
    __syncthreads();
    // (c) stage h_t[b0..b0+15][0..1023] fp16 -> LDS: 32 chunks of 1KB, 8 per wave
    {
      const __fp16* hsrc = hbuf + (size_t)t * 131072 + (size_t)b0 * 1024;
#pragma unroll
      for (int i = 0; i < 8; ++i) {
        int c = wid * 8 + i;
        int row = c >> 1, half = c & 1;
        gload_lds16(hsrc + row * 1024 + half * 512 + lane * 8,
                    (void*)(Asub + row * 2064 + half * 1024));
      }
    }
    __syncthreads();
    // (d) MFMA: A from LDS, B from persistent registers; 3 interleaved gate chains
    {
      const unsigned char* abase = Asub + l15 * 2064 + (kh * 512 + quad * 8) * 2;
#pragma unroll
      for (int kk = 0; kk < 16; ++kk) {
        f16x8 af = *(const f16x8*)(abase + kk * 64);
        acc[0] = MFMA16(af, wf[0][kk], acc[0]);
        acc[1] = MFMA16(af, wf[1][kk], acc[1]);
        acc[2] = MFMA16(af, wf[2][kk], acc[2]);
      }
    }
    // (e) K-half reduction via LDS, activation epilogue on kh1 waves
    if (kh == 0) {
#pragma unroll
      for (int g = 0; g < 3; ++g)
#pragma unroll
        for (int r = 0; r < 4; ++r) gbuf[ch][g][quad * 4 + r][l15] = acc[g][r];
    }
    __syncthreads();
    if (kh == 1) {
#pragma unroll
      for (int r = 0; r < 4; ++r) {
        float gi = acc[0][r] + gbuf[ch][0][quad * 4 + r][l15];
        float gg = acc[1][r] + gbuf[ch][1][quad * 4 + r][l15];
        float go = acc[2][r] + gbuf[ch][2][quad * 4 + r][l15];
        float ct = sigmoid_f(gi) * tanh_f(gg);
        float hN = sigmoid_f(go) * tanh_f(ct);
        int row = b0 + quad * 4 + r;
        if (t == SS - 1) out[(size_t)row * 1024 + mycol] = hN;
        else hbuf[(size_t)(t + 1) * 131072 + (size_t)row * 1024 + mycol] = (__fp16)hN;
      }
    }
    __syncthreads();  // each wave drains own vmcnt before barrier => h stores in L2
    if (t < SS - 1 && tid == 0) {
      // RELAXED agent flag store: executes at IF, NO buffer_wbl2. h visibility to
      // same-XCD consumers comes from the shared L2 (stores drained above).
      __hip_atomic_store(flags + (bg * 32 + n) * 16, t + 1,
                         __ATOMIC_RELAXED, __HIP_MEMORY_SCOPE_AGENT);
    }
  }
}

extern "C" void kernel_launch(void* const* d_in, const int* in_sizes, int n_in,
                              void* d_out, int out_size, void* d_ws, size_t ws_size,
                              hipStream_t stream) {
  const int*   tok  = (const int*)d_in[0];
  const float* emb  = (const float*)d_in[1];
  const float* W_ih = (const float*)d_in[2];
  const float* W_hh = (const float*)d_in[3];
  const float* b_ih = (const float*)d_in[4];
  const float* b_hh = (const float*)d_in[5];
  float* out = (float*)d_out;
  char* ws = (char*)d_ws;

  // ws layout (bytes), total 311,455,744 (~297 MB)
  __fp16* X     = (__fp16*)(ws + 0);              // 33,554,432
  __fp16* Wi3   = (__fp16*)(ws + 33554432);       //  3,145,728
  __fp16* Wh3   = (__fp16*)(ws + 36700160);       //  6,291,456
  float*  bias3 = (float*) (ws + 42991616);       //     12,288
  int*    flags = (int*)   (ws + 43003904);       //     16,384 (256 flags, 64B apart)
  __fp16* hbuf  = (__fp16*)(ws + 43020288);       // 67,108,864 (256 step buffers)
  __fp16* Xp    = (__fp16*)(ws + 110129152);      // 201,326,592

  (void)hipMemsetAsync(flags, 0, 16384, stream);
  (void)hipMemsetAsync(hbuf, 0, 131072 * 2, stream);  // h_0 = 0

  prep_kernel<<<3072, 256, 0, stream>>>(W_ih, W_hh, b_ih, b_hh, Wi3, Wh3, bias3);
  gather_kernel<<<32768, 64, 0, stream>>>(tok, emb, X);
  xp_gemm<<<6144, 256, 0, stream>>>(X, Wi3, bias3, Xp);
  recur_kernel<<<256, 256, 0, stream>>>(Wh3, Xp, hbuf, flags, out);
}